// Round 3
// baseline (468.943 us; speedup 1.0000x reference)
//
#include <hip/hip_runtime.h>
#include <hip/hip_bf16.h>
#include <stdint.h>

#define BATCH_N 65536
#define KDIM 1024
#define NTOT 1536

typedef __bf16 bf16x8 __attribute__((ext_vector_type(8)));
typedef float f32x4 __attribute__((ext_vector_type(4)));

__device__ __forceinline__ unsigned short f2bf(float f) {
    unsigned u = __builtin_bit_cast(unsigned, f);
    u += 0x7FFFu + ((u >> 16) & 1u);   // round-to-nearest-even
    return (unsigned short)(u >> 16);
}

// ---------------------------------------------------------------------------
// Kernel 1: x[b][k] = sum_k(node_memories[id]) + node_embedding[id][k], bf16,
// stored pre-swizzled (k ^= (b&7)<<3) for bank-conflict-free LDS staging.
// ---------------------------------------------------------------------------
__global__ __launch_bounds__(256) void prep_kernel(
    const int* __restrict__ ids,
    const float* __restrict__ mem,
    const float* __restrict__ emb,
    unsigned short* __restrict__ x)
{
    const int b = blockIdx.x;
    const int t = threadIdx.x;
    const int id = ids[b];
    const float4* m4 = (const float4*)(mem + (size_t)id * KDIM);
    const float4* e4 = (const float4*)(emb + (size_t)id * KDIM);
    float4 v = m4[t];
    float s = v.x + v.y + v.z + v.w;
    #pragma unroll
    for (int off = 32; off >= 1; off >>= 1) s += __shfl_down(s, off, 64);
    __shared__ float wsum[4];
    const int lane = t & 63, w = t >> 6;
    if (lane == 0) wsum[w] = s;
    __syncthreads();
    const float tot = wsum[0] + wsum[1] + wsum[2] + wsum[3];
    float4 e = e4[t];
    ushort4 o;
    o.x = f2bf(tot + e.x);
    o.y = f2bf(tot + e.y);
    o.z = f2bf(tot + e.z);
    o.w = f2bf(tot + e.w);
    const int k   = t * 4;
    const int ksw = k ^ ((b & 7) << 3);
    *(ushort4*)(x + (size_t)b * KDIM + ksw) = o;
}

// ---------------------------------------------------------------------------
// Kernel 2: Wt[n][k] = W_{n/512}[k][n%512] in bf16, same pre-swizzle on k.
// ---------------------------------------------------------------------------
__global__ __launch_bounds__(256) void wconv_kernel(
    const float* __restrict__ Wq, const float* __restrict__ Ws,
    const float* __restrict__ Wk, unsigned short* __restrict__ wt)
{
    const int gt = blockIdx.x * 256 + threadIdx.x;   // 0..393215
    const int n  = gt % NTOT;
    const int kb = (gt / NTOT) * 4;
    const float* W = (n < 512) ? Wq : ((n < 1024) ? Ws : Wk);
    const int nn = n & 511;
    ushort4 o;
    o.x = f2bf(W[(size_t)(kb + 0) * 512 + nn]);
    o.y = f2bf(W[(size_t)(kb + 1) * 512 + nn]);
    o.z = f2bf(W[(size_t)(kb + 2) * 512 + nn]);
    o.w = f2bf(W[(size_t)(kb + 3) * 512 + nn]);
    const int ksw = kb ^ ((n & 7) << 3);
    *(ushort4*)(wt + (size_t)n * KDIM + ksw) = o;
}

// ---------------------------------------------------------------------------
// Kernel 3: deep-pipelined GEMM + bias + sigmoid.
//   BM=128, BN=256, BK=64, 512 threads = 8 waves (2M x 4N), 64x64 per wave.
//   Triple-buffered LDS (144 KiB): staging runs 2 K-tiles ahead, counted
//   vmcnt(6) once per K-tile (never 0 in the main loop), raw s_barriers,
//   setprio around the MFMA cluster.  LDS XOR-swizzle via pre-swizzled
//   global source (T2), bijective XCD swizzle (T1).
// Ledger (loads: 6 per K-tile, order A0 A1 B0 B1 B2 B3):
//   prologue: stage K0,K1 (12 loads), vmcnt(6) -> K0 done, barrier.
//   tile k: phase0 reads kk=0 of buf[k%3], stages A0,A1,B0 of K(k+2);
//           phase1 reads kk=1, stages B1,B2,B3; vmcnt(6) -> K(k+1) done.
//   WAR: buf[(k+2)%3] last read at tile k-1; all its ds_reads are lgkm-
//        drained before tile k-1's final barrier; staging issues after it.
// ---------------------------------------------------------------------------
#define BM 128
#define BN 256
#define BK 64
#define MT (BATCH_N / BM)   // 512
#define NT (NTOT / BN)      // 6
#define NWG (MT * NT)       // 3072 = 8 * 384, 384 % 6 == 0 -> bijective

#define BAR() asm volatile("s_barrier" ::: "memory")

__global__ __launch_bounds__(512, 2) void gemm_kernel(
    const unsigned short* __restrict__ X,    // [65536][1024] bf16, swizzled
    const unsigned short* __restrict__ Wt,   // [1536][1024]  bf16, swizzled
    const float* __restrict__ bq, const float* __restrict__ bs,
    const float* __restrict__ bk, float* __restrict__ out)
{
    __shared__ __align__(16) unsigned short sA[3][BM * BK];  // 3 x 16 KiB
    __shared__ __align__(16) unsigned short sB[3][BN * BK];  // 3 x 32 KiB

    const int tid  = threadIdx.x;
    const int xcd  = blockIdx.x & 7;
    const int idx  = blockIdx.x >> 3;
    const int wgid = xcd * (NWG / 8) + idx;
    const int nt   = wgid % NT;              // n fastest: A-tile L2 reuse
    const int mt   = wgid / NT;
    const int m0   = mt * BM;
    const int n0   = nt * BN;
    const int wid  = tid >> 6;
    const int lane = tid & 63;
    const int wm   = wid >> 2;               // 0..1
    const int wn   = wid & 3;                // 0..3
    const int r16  = lane & 15;
    const int kb0  = (lane >> 4) << 4;       // 0,16,32,48 (bytes)
    const int ksw  = (r16 & 7) << 4;         // LDS XOR swizzle (bytes)

    f32x4 acc[4][4];
    #pragma unroll
    for (int i = 0; i < 4; i++)
        #pragma unroll
        for (int j = 0; j < 4; j++)
            acc[i][j] = f32x4{0.f, 0.f, 0.f, 0.f};

    // staging source base (thread-fixed): row = tid>>3, 16B chunk = tid&7
    const unsigned short* gA = X  + (size_t)(m0 + (tid >> 3)) * KDIM + (tid & 7) * 8;
    const unsigned short* gB = Wt + (size_t)(n0 + (tid >> 3)) * KDIM + (tid & 7) * 8;
    const int ldst = (tid & 448) * 8;        // wave-uniform elem offset in chunk

#define STA(buf, kt, c) __builtin_amdgcn_global_load_lds( \
    (const __attribute__((address_space(1))) void*)(gA + (size_t)(c) * 64 * KDIM + (kt) * BK), \
    (__attribute__((address_space(3))) void*)(&sA[buf][(c) * 4096 + ldst]), 16, 0, 0)
#define STB(buf, kt, c) __builtin_amdgcn_global_load_lds( \
    (const __attribute__((address_space(1))) void*)(gB + (size_t)(c) * 64 * KDIM + (kt) * BK), \
    (__attribute__((address_space(3))) void*)(&sB[buf][(c) * 4096 + ldst]), 16, 0, 0)

#define PHASE(rb, kkc, STAGE_STMTS, VMW) do {                                   \
    const char* pa = (const char*)&sA[rb][0];                                    \
    const char* pb = (const char*)&sB[rb][0];                                    \
    bf16x8 af[4], bfr[4];                                                        \
    _Pragma("unroll")                                                            \
    for (int i = 0; i < 4; i++)                                                  \
        af[i] = *(const bf16x8*)(pa + (wm * 64 + i * 16 + r16) * 128             \
                                    + ((kb0 + (kkc) * 64) ^ ksw));               \
    _Pragma("unroll")                                                            \
    for (int j = 0; j < 4; j++)                                                  \
        bfr[j] = *(const bf16x8*)(pb + (wn * 64 + j * 16 + r16) * 128            \
                                     + ((kb0 + (kkc) * 64) ^ ksw));              \
    STAGE_STMTS;                                                                 \
    BAR();                                                                       \
    asm volatile("s_waitcnt lgkmcnt(0)" ::: "memory");                           \
    __builtin_amdgcn_s_setprio(1);                                               \
    _Pragma("unroll")                                                            \
    for (int i = 0; i < 4; i++)                                                  \
        _Pragma("unroll")                                                        \
        for (int j = 0; j < 4; j++)                                              \
            acc[i][j] = __builtin_amdgcn_mfma_f32_16x16x32_bf16(                 \
                af[i], bfr[j], acc[i][j], 0, 0, 0);                              \
    __builtin_amdgcn_s_setprio(0);                                               \
    VMW;                                                                         \
    BAR();                                                                       \
} while (0)

    // ---- prologue: stage K-tiles 0 and 1 ----
    STA(0, 0, 0); STA(0, 0, 1); STB(0, 0, 0); STB(0, 0, 1); STB(0, 0, 2); STB(0, 0, 3);
    STA(1, 1, 0); STA(1, 1, 1); STB(1, 1, 0); STB(1, 1, 1); STB(1, 1, 2); STB(1, 1, 3);
    asm volatile("s_waitcnt vmcnt(6)" ::: "memory");   // K0 fully staged
    BAR();

    // ---- main loop: K-tiles 0..13 stage K(k+2) ----
    int rb = 0, wb = 2;
    for (int k = 0; k < 14; ++k) {
        const int kt = k + 2;
        PHASE(rb, 0, ({ STA(wb, kt, 0); STA(wb, kt, 1); STB(wb, kt, 0); }), (void)0);
        PHASE(rb, 1, ({ STB(wb, kt, 1); STB(wb, kt, 2); STB(wb, kt, 3); }),
              asm volatile("s_waitcnt vmcnt(6)" ::: "memory"));
        rb = (rb == 2) ? 0 : rb + 1;
        wb = (wb == 2) ? 0 : wb + 1;
    }
    // ---- K-tile 14: no staging, drain the last 6 loads before K-tile 15 ----
    PHASE(rb, 0, (void)0, (void)0);
    PHASE(rb, 1, (void)0, asm volatile("s_waitcnt vmcnt(0)" ::: "memory"));
    rb = (rb == 2) ? 0 : rb + 1;
    // ---- K-tile 15 ----
    PHASE(rb, 0, (void)0, (void)0);
    PHASE(rb, 1, (void)0, (void)0);

    // ---- epilogue: bias + sigmoid, nontemporal fp32 stores ----
    // C/D layout: col=lane&15, row=(lane>>4)*4+reg  [m89/m91]
    const int grp = nt >> 1;                        // 0=q, 1=s, 2=k
    const float* bias = (grp == 0) ? bq : ((grp == 1) ? bs : bk);
    float* obase = out + (size_t)grp * ((size_t)BATCH_N * 512);
    #pragma unroll
    for (int j = 0; j < 4; j++) {
        const int col = (nt & 1) * 256 + wn * 64 + j * 16 + r16;
        const float bv = bias[col];
        #pragma unroll
        for (int i = 0; i < 4; i++) {
            const int rbase = m0 + wm * 64 + i * 16 + ((lane >> 4) << 2);
            #pragma unroll
            for (int r = 0; r < 4; r++) {
                float v = acc[i][j][r] + bv;
                v = 1.0f / (1.0f + __expf(-v));
                __builtin_nontemporal_store(v, &obase[(size_t)(rbase + r) * 512 + col]);
            }
        }
    }
#undef STA
#undef STB
#undef PHASE
}

extern "C" void kernel_launch(void* const* d_in, const int* in_sizes, int n_in,
                              void* d_out, int out_size, void* d_ws, size_t ws_size,
                              hipStream_t stream) {
    const int*   ids = (const int*)d_in[0];
    const float* mem = (const float*)d_in[1];
    const float* emb = (const float*)d_in[2];
    const float* Wq  = (const float*)d_in[3];
    const float* bq  = (const float*)d_in[4];
    const float* Ws  = (const float*)d_in[5];
    const float* bs  = (const float*)d_in[6];
    const float* Wk  = (const float*)d_in[7];
    const float* bk  = (const float*)d_in[8];
    float* out = (float*)d_out;

    unsigned short* x  = (unsigned short*)d_ws;              // 65536*1024 bf16 = 128 MiB
    unsigned short* wt = x + (size_t)BATCH_N * KDIM;         // 1536*1024  bf16 = 3 MiB

    hipLaunchKernelGGL(wconv_kernel, dim3(NTOT), dim3(256), 0, stream, Wq, Ws, Wk, wt);
    hipLaunchKernelGGL(prep_kernel, dim3(BATCH_N), dim3(256), 0, stream, ids, mem, emb, x);
    hipLaunchKernelGGL(gemm_kernel, dim3(NWG), dim3(512), 0, stream,
                       x, wt, bq, bs, bk, out);
}

// Round 4
// 421.000 us; speedup vs baseline: 1.1139x; 1.1139x over previous
//
#include <hip/hip_runtime.h>
#include <hip/hip_bf16.h>
#include <stdint.h>

#define BATCH_N 65536
#define KDIM 1024
#define NTOT 1536

typedef __bf16 bf16x8 __attribute__((ext_vector_type(8)));
typedef float f32x4 __attribute__((ext_vector_type(4)));

__device__ __forceinline__ unsigned short f2bf(float f) {
    unsigned u = __builtin_bit_cast(unsigned, f);
    u += 0x7FFFu + ((u >> 16) & 1u);   // round-to-nearest-even
    return (unsigned short)(u >> 16);
}

// ---------------------------------------------------------------------------
// Kernel 1: x[b][k] = sum_k(node_memories[id]) + node_embedding[id][k], bf16,
// stored pre-swizzled (k ^= (b&7)<<3) for bank-conflict-free LDS staging.
// ---------------------------------------------------------------------------
__global__ __launch_bounds__(256) void prep_kernel(
    const int* __restrict__ ids,
    const float* __restrict__ mem,
    const float* __restrict__ emb,
    unsigned short* __restrict__ x)
{
    const int b = blockIdx.x;
    const int t = threadIdx.x;
    const int id = ids[b];
    const float4* m4 = (const float4*)(mem + (size_t)id * KDIM);
    const float4* e4 = (const float4*)(emb + (size_t)id * KDIM);
    float4 v = m4[t];
    float s = v.x + v.y + v.z + v.w;
    #pragma unroll
    for (int off = 32; off >= 1; off >>= 1) s += __shfl_down(s, off, 64);
    __shared__ float wsum[4];
    const int lane = t & 63, w = t >> 6;
    if (lane == 0) wsum[w] = s;
    __syncthreads();
    const float tot = wsum[0] + wsum[1] + wsum[2] + wsum[3];
    float4 e = e4[t];
    ushort4 o;
    o.x = f2bf(tot + e.x);
    o.y = f2bf(tot + e.y);
    o.z = f2bf(tot + e.z);
    o.w = f2bf(tot + e.w);
    const int k   = t * 4;
    const int ksw = k ^ ((b & 7) << 3);
    *(ushort4*)(x + (size_t)b * KDIM + ksw) = o;
}

// ---------------------------------------------------------------------------
// Kernel 2: Wt[n][k] = W_{n/512}[k][n%512] in bf16, same pre-swizzle on k.
// ---------------------------------------------------------------------------
__global__ __launch_bounds__(256) void wconv_kernel(
    const float* __restrict__ Wq, const float* __restrict__ Ws,
    const float* __restrict__ Wk, unsigned short* __restrict__ wt)
{
    const int gt = blockIdx.x * 256 + threadIdx.x;   // 0..393215
    const int n  = gt % NTOT;
    const int kb = (gt / NTOT) * 4;
    const float* W = (n < 512) ? Wq : ((n < 1024) ? Ws : Wk);
    const int nn = n & 511;
    ushort4 o;
    o.x = f2bf(W[(size_t)(kb + 0) * 512 + nn]);
    o.y = f2bf(W[(size_t)(kb + 1) * 512 + nn]);
    o.z = f2bf(W[(size_t)(kb + 2) * 512 + nn]);
    o.w = f2bf(W[(size_t)(kb + 3) * 512 + nn]);
    const int ksw = kb ^ ((n & 7) << 3);
    *(ushort4*)(wt + (size_t)n * KDIM + ksw) = o;
}

// ---------------------------------------------------------------------------
// Kernel 3: 256x256 8-phase GEMM (m201-style) + bias + sigmoid.
//   512 threads = 8 waves (2M x 4N); per-wave 128x64 output, decomposed as
//   2x2 quadrants of 64x32 INTERLEAVED across tile halves:
//     A rows: qa*128 + wm*64 + i*16   (qa = A-half)
//     B cols: qb*128 + wn*32 + j*16   (qb = B-half)
//   so each staged half-tile is consumed in exactly one phase role:
//     ph0: Aq0+Bq0, ph1: Bq1, ph2: Aq1, ph3: Bq0   (per K-tile)
//   LDS 128 KiB: {A,B} x [2 slots][2 halves][128 rows][64 k] bf16.
//   Staging: 1 half-tile per phase (2 global_load_lds per thread), plan:
//     ph0: s1.Ah1<-2t+1  ph1: s1.Bh0<-2t+1  ph2: s1.Bh1<-2t+1  ph3: s0.Ah0<-2t+2
//     ph4: s0.Ah1<-2t+2  ph5: s0.Bh0<-2t+2  ph6: s0.Bh1<-2t+2  ph7: s1.Ah0<-2t+3
//   vmcnt(2) at end of ph3 (retires tile 2t+1's 8 loads) and ph7 (retires
//   tile 2t+2's 8) -- counted, never 0 in the main loop.
//   Prologue: t0 full + t1.Ah0 (10 loads), vmcnt(2).  Tail: vmcnt(0) at ph3.
// ---------------------------------------------------------------------------
#define BM 256
#define BN 256
#define BK 64
#define MT (BATCH_N / BM)   // 256
#define NT (NTOT / BN)      // 6
#define NWG (MT * NT)       // 1536 = 8 * 192, 192 % 6 == 0 -> bijective

#define BAR() asm volatile("s_barrier" ::: "memory")
#define LGKM0() asm volatile("s_waitcnt lgkmcnt(0)" ::: "memory")
#define VM2() asm volatile("s_waitcnt vmcnt(2)" ::: "memory")
#define VM0() asm volatile("s_waitcnt vmcnt(0)" ::: "memory")
#define AS1 __attribute__((address_space(1)))
#define AS3 __attribute__((address_space(3)))

__global__ __launch_bounds__(512, 2) void gemm_kernel(
    const unsigned short* __restrict__ X,    // [65536][1024] bf16, swizzled
    const unsigned short* __restrict__ Wt,   // [1536][1024]  bf16, swizzled
    const float* __restrict__ bq, const float* __restrict__ bs,
    const float* __restrict__ bk, float* __restrict__ out)
{
    __shared__ __align__(16) unsigned short sA[32768];   // 64 KiB
    __shared__ __align__(16) unsigned short sB[32768];   // 64 KiB

    const int tid  = threadIdx.x;
    const int xcd  = blockIdx.x & 7;
    const int idx  = blockIdx.x >> 3;
    const int wgid = xcd * (NWG / 8) + idx;
    const int nt   = wgid % NT;              // n fastest: A-panel L2 reuse
    const int mt   = wgid / NT;
    const int m0   = mt * BM;
    const int n0   = nt * BN;
    const int wid  = tid >> 6;
    const int lane = tid & 63;
    const int wm   = wid >> 2;               // 0..1
    const int wn   = wid & 3;                // 0..3
    const int r16  = lane & 15;
    const int kb0  = (lane >> 4) << 4;       // 0,16,32,48 (bytes within k-half)
    const int ksw  = (r16 & 7) << 4;         // LDS XOR swizzle (bytes)

    f32x4 acc[8][4];
    #pragma unroll
    for (int i = 0; i < 8; i++)
        #pragma unroll
        for (int j = 0; j < 4; j++)
            acc[i][j] = f32x4{0.f, 0.f, 0.f, 0.f};

    bf16x8 af[4][2], bfr[2][2];

    // staging source base: row = tid>>3 (+64 per c), 16B chunk = tid&7
    const unsigned short* gA = X  + (size_t)(m0 + (tid >> 3)) * KDIM + (tid & 7) * 8;
    const unsigned short* gB = Wt + (size_t)(n0 + (tid >> 3)) * KDIM + (tid & 7) * 8;
    const int ldst = (tid & 448) * 8;        // wave-uniform LDS elem offset

#define STAGE_A(slot, h, kt) do {                                               \
    _Pragma("unroll")                                                            \
    for (int c = 0; c < 2; ++c)                                                  \
        __builtin_amdgcn_global_load_lds(                                        \
            (const AS1 void*)(gA + (size_t)((h) * 128 + c * 64) * KDIM + (kt) * BK), \
            (AS3 void*)(&sA[((slot) * 2 + (h)) * 8192 + c * 4096 + ldst]),       \
            16, 0, 0);                                                           \
} while (0)
#define STAGE_B(slot, h, kt) do {                                               \
    _Pragma("unroll")                                                            \
    for (int c = 0; c < 2; ++c)                                                  \
        __builtin_amdgcn_global_load_lds(                                        \
            (const AS1 void*)(gB + (size_t)((h) * 128 + c * 64) * KDIM + (kt) * BK), \
            (AS3 void*)(&sB[((slot) * 2 + (h)) * 8192 + c * 4096 + ldst]),       \
            16, 0, 0);                                                           \
} while (0)

#define LDA(slot, qa) do {                                                      \
    const char* p = (const char*)&sA[((slot) * 2 + (qa)) * 8192];                \
    _Pragma("unroll")                                                            \
    for (int i = 0; i < 4; ++i)                                                  \
        _Pragma("unroll")                                                        \
        for (int kk = 0; kk < 2; ++kk)                                           \
            af[i][kk] = *(const bf16x8*)(p + (wm * 64 + i * 16 + r16) * 128      \
                                           + ((kk * 64 + kb0) ^ ksw));           \
} while (0)
#define LDB(slot, qb) do {                                                      \
    const char* p = (const char*)&sB[((slot) * 2 + (qb)) * 8192];                \
    _Pragma("unroll")                                                            \
    for (int j = 0; j < 2; ++j)                                                  \
        _Pragma("unroll")                                                        \
        for (int kk = 0; kk < 2; ++kk)                                           \
            bfr[j][kk] = *(const bf16x8*)(p + (wn * 32 + j * 16 + r16) * 128     \
                                            + ((kk * 64 + kb0) ^ ksw));          \
} while (0)

#define MM(QA, QB) do {                                                         \
    __builtin_amdgcn_s_setprio(1);                                               \
    _Pragma("unroll")                                                            \
    for (int i = 0; i < 4; ++i)                                                  \
        _Pragma("unroll")                                                        \
        for (int j = 0; j < 2; ++j)                                              \
            _Pragma("unroll")                                                    \
            for (int kk = 0; kk < 2; ++kk)                                       \
                acc[(QA) * 4 + i][(QB) * 2 + j] =                                \
                    __builtin_amdgcn_mfma_f32_16x16x32_bf16(                     \
                        af[i][kk], bfr[j][kk], acc[(QA) * 4 + i][(QB) * 2 + j],  \
                        0, 0, 0);                                                \
    __builtin_amdgcn_s_setprio(0);                                               \
} while (0)

// one phase: {reads ; stage} -> barrier -> lgkm0 -> MFMA -> [wait] -> barrier
#define PH(QA, QB, LOADS, STAGES, WAIT) do {                                    \
    LOADS; STAGES; BAR(); LGKM0(); MM(QA, QB); WAIT; BAR();                      \
} while (0)

    // ---- prologue: tile0 full + tile1.Ah0 (10 loads) ----
    STAGE_A(0, 0, 0); STAGE_A(0, 1, 0); STAGE_B(0, 0, 0); STAGE_B(0, 1, 0);
    STAGE_A(1, 0, 1);
    VM2();                       // tile0's 8 loads retired
    BAR();

    // ---- main loop: t = 0..6, tiles {2t, 2t+1}, staging {2t+1..2t+3} ----
    #pragma unroll 1
    for (int t = 0; t < 7; ++t) {
        const int ka = 2 * t + 1, kb2 = 2 * t + 2, kc = 2 * t + 3;
        PH(0, 0, ({ LDA(0, 0); LDB(0, 0); }), STAGE_A(1, 1, ka), (void)0);
        PH(0, 1, LDB(0, 1),                   STAGE_B(1, 0, ka), (void)0);
        PH(1, 1, LDA(0, 1),                   STAGE_B(1, 1, ka), (void)0);
        PH(1, 0, LDB(0, 0),                   STAGE_A(0, 0, kb2), VM2());
        PH(0, 0, ({ LDA(1, 0); LDB(1, 0); }), STAGE_A(0, 1, kb2), (void)0);
        PH(0, 1, LDB(1, 1),                   STAGE_B(0, 0, kb2), (void)0);
        PH(1, 1, LDA(1, 1),                   STAGE_B(0, 1, kb2), (void)0);
        PH(1, 0, LDB(1, 0),                   STAGE_A(1, 0, kc),  VM2());
    }
    // ---- tail: tiles 14 (s0), 15 (s1); finish staging tile 15 ----
    PH(0, 0, ({ LDA(0, 0); LDB(0, 0); }), STAGE_A(1, 1, 15), (void)0);
    PH(0, 1, LDB(0, 1),                   STAGE_B(1, 0, 15), (void)0);
    PH(1, 1, LDA(0, 1),                   STAGE_B(1, 1, 15), (void)0);
    PH(1, 0, LDB(0, 0),                   (void)0,           VM0());
    PH(0, 0, ({ LDA(1, 0); LDB(1, 0); }), (void)0,           (void)0);
    PH(0, 1, LDB(1, 1),                   (void)0,           (void)0);
    PH(1, 1, LDA(1, 1),                   (void)0,           (void)0);
    PH(1, 0, LDB(1, 0),                   (void)0,           (void)0);

    // ---- epilogue: bias + sigmoid, nontemporal fp32 stores ----
    // C/D layout: col=lane&15, row=(lane>>4)*4+reg  [m89/m91]
    const int grp = nt >> 1;                        // 0=q, 1=s, 2=k
    const float* bias = (grp == 0) ? bq : ((grp == 1) ? bs : bk);
    float* obase = out + (size_t)grp * ((size_t)BATCH_N * 512);
    const int cb = (nt & 1) * 256;
    #pragma unroll
    for (int qb = 0; qb < 2; ++qb)
        #pragma unroll
        for (int j = 0; j < 2; ++j) {
            const int col = cb + qb * 128 + wn * 32 + j * 16 + r16;
            const float bv = bias[col];
            #pragma unroll
            for (int qa = 0; qa < 2; ++qa)
                #pragma unroll
                for (int i = 0; i < 4; ++i) {
                    const int rbase = m0 + qa * 128 + wm * 64 + i * 16 + ((lane >> 4) << 2);
                    #pragma unroll
                    for (int r = 0; r < 4; ++r) {
                        float v = acc[qa * 4 + i][qb * 2 + j][r] + bv;
                        v = 1.0f / (1.0f + __expf(-v));
                        __builtin_nontemporal_store(v, &obase[(size_t)(rbase + r) * 512 + col]);
                    }
                }
        }
#undef STAGE_A
#undef STAGE_B
#undef LDA
#undef LDB
#undef MM
#undef PH
}

extern "C" void kernel_launch(void* const* d_in, const int* in_sizes, int n_in,
                              void* d_out, int out_size, void* d_ws, size_t ws_size,
                              hipStream_t stream) {
    const int*   ids = (const int*)d_in[0];
    const float* mem = (const float*)d_in[1];
    const float* emb = (const float*)d_in[2];
    const float* Wq  = (const float*)d_in[3];
    const float* bq  = (const float*)d_in[4];
    const float* Ws  = (const float*)d_in[5];
    const float* bs  = (const float*)d_in[6];
    const float* Wk  = (const float*)d_in[7];
    const float* bk  = (const float*)d_in[8];
    float* out = (float*)d_out;

    unsigned short* x  = (unsigned short*)d_ws;              // 65536*1024 bf16 = 128 MiB
    unsigned short* wt = x + (size_t)BATCH_N * KDIM;         // 1536*1024  bf16 = 3 MiB

    hipLaunchKernelGGL(wconv_kernel, dim3(NTOT), dim3(256), 0, stream, Wq, Ws, Wk, wt);
    hipLaunchKernelGGL(prep_kernel, dim3(BATCH_N), dim3(256), 0, stream, ids, mem, emb, x);
    hipLaunchKernelGGL(gemm_kernel, dim3(NWG), dim3(512), 0, stream,
                       x, wt, bq, bs, bk, out);
}

// Round 6
// 411.953 us; speedup vs baseline: 1.1383x; 1.0220x over previous
//
#include <hip/hip_runtime.h>
#include <hip/hip_bf16.h>
#include <stdint.h>

#define BATCH_N 65536
#define KDIM 1024
#define NTOT 1536

typedef __bf16 bf16x8 __attribute__((ext_vector_type(8)));
typedef float f32x4 __attribute__((ext_vector_type(4)));

__device__ __forceinline__ unsigned short f2bf(float f) {
    unsigned u = __builtin_bit_cast(unsigned, f);
    u += 0x7FFFu + ((u >> 16) & 1u);   // round-to-nearest-even
    return (unsigned short)(u >> 16);
}

// ---------------------------------------------------------------------------
// Kernel 1: x[b][k] = sum(node_memories[id]) + node_embedding[id][k], bf16,
// pre-swizzled (k ^= (b&7)<<3).  One WAVE per row; each lane owns 4 float4
// chunks at k = q*256 + lane*4 (full 1024 coverage), butterfly reduce.
// ---------------------------------------------------------------------------
__global__ __launch_bounds__(256) void prep_kernel(
    const int* __restrict__ ids,
    const float* __restrict__ mem,
    const float* __restrict__ emb,
    unsigned short* __restrict__ x)
{
    const int b    = blockIdx.x * 4 + (threadIdx.x >> 6);
    const int lane = threadIdx.x & 63;
    const int id   = ids[b];
    const float4* m4 = (const float4*)(mem + (size_t)id * KDIM) + lane;
    const float4* e4 = (const float4*)(emb + (size_t)id * KDIM) + lane;
    float4 v0 = m4[0];
    float4 v1 = m4[64];
    float4 v2 = m4[128];
    float4 v3 = m4[192];
    float s = (v0.x + v0.y + v0.z + v0.w) + (v1.x + v1.y + v1.z + v1.w)
            + (v2.x + v2.y + v2.z + v2.w) + (v3.x + v3.y + v3.z + v3.w);
    #pragma unroll
    for (int off = 1; off < 64; off <<= 1) s += __shfl_xor(s, off, 64);
    unsigned short* xb = x + (size_t)b * KDIM;
    #pragma unroll
    for (int q = 0; q < 4; ++q) {
        float4 e = e4[q * 64];
        ushort4 o;
        o.x = f2bf(s + e.x);
        o.y = f2bf(s + e.y);
        o.z = f2bf(s + e.z);
        o.w = f2bf(s + e.w);
        const int k   = q * 256 + lane * 4;
        const int ksw = k ^ ((b & 7) << 3);
        *(ushort4*)(xb + ksw) = o;
    }
}

// ---------------------------------------------------------------------------
// Kernel 2: Wt[n][k] = W_{n/512}[k][n%512] in bf16, same pre-swizzle on k.
// ---------------------------------------------------------------------------
__global__ __launch_bounds__(256) void wconv_kernel(
    const float* __restrict__ Wq, const float* __restrict__ Ws,
    const float* __restrict__ Wk, unsigned short* __restrict__ wt)
{
    const int gt = blockIdx.x * 256 + threadIdx.x;   // 0..393215
    const int n  = gt % NTOT;
    const int kb = (gt / NTOT) * 4;
    const float* W = (n < 512) ? Wq : ((n < 1024) ? Ws : Wk);
    const int nn = n & 511;
    ushort4 o;
    o.x = f2bf(W[(size_t)(kb + 0) * 512 + nn]);
    o.y = f2bf(W[(size_t)(kb + 1) * 512 + nn]);
    o.z = f2bf(W[(size_t)(kb + 2) * 512 + nn]);
    o.w = f2bf(W[(size_t)(kb + 3) * 512 + nn]);
    const int ksw = kb ^ ((n & 7) << 3);
    *(ushort4*)(wt + (size_t)n * KDIM + ksw) = o;
}

// ---------------------------------------------------------------------------
// Kernel 3: 256x256 GEMM, 3 sub-phases per K-tile (48 barriers total).
//   512 threads = 8 waves (2M x 4N); per-wave 128x64 output.
//   P1: BAR; MM(qa=0) [32 MFMA]; RD_A(q1) (slot t, safe); STAGE B(t+1).
//   P2: BAR; MM(qa=1); STAGE A(t+2); vmcnt(4)  [counted, never 0 mid-loop].
//   P3: BAR  (-> every wave past its vmcnt => tile t+1 globally visible);
//       RD_A(t+1,q0); RD_B(t+1)  -- consumed after P1's next BAR.
//   RACE FIX vs r5: tile t+1 reads now issue only after the vmcnt->BARRIER
//   pair (vmcnt is per-wave; the barrier makes retirement collective).
//   LDS 128 KiB: {A,B} x [2 slots][2 halves][128 rows][64 k] bf16.
// Ledger: prologue A(t0),B(t0),A(t1)=12, vm4 -> t0 retired.  Steady state:
//   start of tile t: A(t+1) in flight (4); P1 +B(t+1)=8; P2 +A(t+2)=12,
//   vm4 retires A(t+1),B(t+1) -> 4.  Tail t=14: vm0; t=15: no staging.
// ---------------------------------------------------------------------------
#define BM 256
#define BN 256
#define BK 64
#define MT (BATCH_N / BM)   // 256
#define NT (NTOT / BN)      // 6
#define NWG (MT * NT)       // 1536 = 8 * 192, 192 % 6 == 0 -> bijective

#define BAR() asm volatile("s_barrier" ::: "memory")
#define VM4() asm volatile("s_waitcnt vmcnt(4)" ::: "memory")
#define VM0() asm volatile("s_waitcnt vmcnt(0)" ::: "memory")
#define AS1 __attribute__((address_space(1)))
#define AS3 __attribute__((address_space(3)))

__global__ __launch_bounds__(512, 2) void gemm_kernel(
    const unsigned short* __restrict__ X,    // [65536][1024] bf16, swizzled
    const unsigned short* __restrict__ Wt,   // [1536][1024]  bf16, swizzled
    const float* __restrict__ bq, const float* __restrict__ bs,
    const float* __restrict__ bk, float* __restrict__ out)
{
    __shared__ __align__(16) unsigned short sA[32768];   // 2 slots x 32 KiB
    __shared__ __align__(16) unsigned short sB[32768];

    const int tid  = threadIdx.x;
    const int xcd  = blockIdx.x & 7;
    const int idx  = blockIdx.x >> 3;
    const int wgid = xcd * (NWG / 8) + idx;
    const int nt   = wgid % NT;              // n fastest: A-panel L2 reuse
    const int mt   = wgid / NT;
    const int m0   = mt * BM;
    const int n0   = nt * BN;
    const int wid  = tid >> 6;
    const int lane = tid & 63;
    const int wm   = wid >> 2;               // 0..1
    const int wn   = wid & 3;                // 0..3
    const int r16  = lane & 15;
    const int kb0  = (lane >> 4) << 4;       // 0,16,32,48 (bytes)
    const int ksw  = (r16 & 7) << 4;         // LDS XOR swizzle (bytes)

    f32x4 acc[8][4];
    #pragma unroll
    for (int i = 0; i < 8; i++)
        #pragma unroll
        for (int j = 0; j < 4; j++)
            acc[i][j] = f32x4{0.f, 0.f, 0.f, 0.f};

    bf16x8 af[4][2], bfr[4][2];

    const unsigned short* gA = X  + (size_t)(m0 + (tid >> 3)) * KDIM + (tid & 7) * 8;
    const unsigned short* gB = Wt + (size_t)(n0 + (tid >> 3)) * KDIM + (tid & 7) * 8;
    const int ldst = (tid & 448) * 8;        // wave-uniform LDS elem offset

// stage BOTH halves of one operand for K-tile kt (4 loads/thread)
#define STAGE_A(slot, kt) do {                                                  \
    _Pragma("unroll")                                                            \
    for (int h = 0; h < 2; ++h)                                                  \
        _Pragma("unroll")                                                        \
        for (int c = 0; c < 2; ++c)                                              \
            __builtin_amdgcn_global_load_lds(                                    \
                (const AS1 void*)(gA + (size_t)(h * 128 + c * 64) * KDIM + (kt) * BK), \
                (AS3 void*)(&sA[(slot) * 16384 + h * 8192 + c * 4096 + ldst]),   \
                16, 0, 0);                                                       \
} while (0)
#define STAGE_B(slot, kt) do {                                                  \
    _Pragma("unroll")                                                            \
    for (int h = 0; h < 2; ++h)                                                  \
        _Pragma("unroll")                                                        \
        for (int c = 0; c < 2; ++c)                                              \
            __builtin_amdgcn_global_load_lds(                                    \
                (const AS1 void*)(gB + (size_t)(h * 128 + c * 64) * KDIM + (kt) * BK), \
                (AS3 void*)(&sB[(slot) * 16384 + h * 8192 + c * 4096 + ldst]),   \
                16, 0, 0);                                                       \
} while (0)

#define RD_A(slot, qa) do {                                                     \
    const char* p = (const char*)&sA[(slot) * 16384 + (qa) * 8192];              \
    _Pragma("unroll")                                                            \
    for (int i = 0; i < 4; ++i)                                                  \
        _Pragma("unroll")                                                        \
        for (int kk = 0; kk < 2; ++kk)                                           \
            af[i][kk] = *(const bf16x8*)(p + (wm * 64 + i * 16 + r16) * 128      \
                                           + ((kk * 64 + kb0) ^ ksw));           \
} while (0)
#define RD_B(slot) do {                                                         \
    const char* p = (const char*)&sB[(slot) * 16384 + (wn >> 1) * 8192];         \
    _Pragma("unroll")                                                            \
    for (int j = 0; j < 4; ++j)                                                  \
        _Pragma("unroll")                                                        \
        for (int kk = 0; kk < 2; ++kk)                                           \
            bfr[j][kk] = *(const bf16x8*)(p + ((wn & 1) * 64 + j * 16 + r16) * 128 \
                                            + ((kk * 64 + kb0) ^ ksw));          \
} while (0)

// 32 MFMAs: qa-half rows x all 4 B-frags x K=64.  QA is a literal constant.
#define MM(QA) do {                                                             \
    __builtin_amdgcn_s_setprio(1);                                               \
    _Pragma("unroll")                                                            \
    for (int i = 0; i < 4; ++i)                                                  \
        _Pragma("unroll")                                                        \
        for (int j = 0; j < 4; ++j)                                              \
            _Pragma("unroll")                                                    \
            for (int kk = 0; kk < 2; ++kk)                                       \
                acc[(QA) * 4 + i][j] = __builtin_amdgcn_mfma_f32_16x16x32_bf16(  \
                    af[i][kk], bfr[j][kk], acc[(QA) * 4 + i][j], 0, 0, 0);       \
    __builtin_amdgcn_s_setprio(0);                                               \
} while (0)

    // ---- prologue ----
    STAGE_A(0, 0); STAGE_B(0, 0); STAGE_A(1, 1);
    VM4();                        // tile0's 8 loads retired (per wave)
    BAR();                        // -> tile0 globally visible
    RD_A(0, 0); RD_B(0);          // tile0 reads (consumed after next BAR)

    // ---- main loop: tiles 0..13 ----
    #pragma unroll 1
    for (int t = 0; t < 14; ++t) {
        const int s = t & 1, s1 = s ^ 1;
        // P1: compute qa=0 of tile t; prefetch af(q1); stage B(t+1)
        BAR();
        MM(0);
        RD_A(s, 1);
        STAGE_B(s1, t + 1);
        // P2: compute qa=1; stage A(t+2); counted vmcnt
        BAR();
        MM(1);
        STAGE_A(s, t + 2);
        VM4();
        // P3: barrier makes tile t+1 retirement collective, then read it
        BAR();
        RD_A(s1, 0); RD_B(s1);
    }
    // ---- tile 14 (slot 0) ----
    BAR(); MM(0); RD_A(0, 1); STAGE_B(1, 15);
    BAR(); MM(1); VM0();
    BAR(); RD_A(1, 0); RD_B(1);
    // ---- tile 15 (slot 1) ----
    BAR(); MM(0); RD_A(1, 1);
    BAR(); MM(1);

    // ---- epilogue: bias + sigmoid, nontemporal fp32 stores ----
    // C/D layout: col=lane&15, row=(lane>>4)*4+reg  [m89/m91]
    const int grp = nt >> 1;                        // 0=q, 1=s, 2=k
    const float* bias = (grp == 0) ? bq : ((grp == 1) ? bs : bk);
    float* obase = out + (size_t)grp * ((size_t)BATCH_N * 512);
    const int cb = (nt & 1) * 256;
    #pragma unroll
    for (int j = 0; j < 4; ++j) {
        const int col = cb + wn * 64 + j * 16 + r16;
        const float bv = bias[col];
        #pragma unroll
        for (int qa = 0; qa < 2; ++qa)
            #pragma unroll
            for (int i = 0; i < 4; ++i) {
                const int rbase = m0 + qa * 128 + wm * 64 + i * 16 + ((lane >> 4) << 2);
                #pragma unroll
                for (int r = 0; r < 4; ++r) {
                    float v = acc[qa * 4 + i][j][r] + bv;
                    v = 1.0f / (1.0f + __expf(-v));
                    __builtin_nontemporal_store(v, &obase[(size_t)(rbase + r) * 512 + col]);
                }
            }
    }
#undef STAGE_A
#undef STAGE_B
#undef RD_A
#undef RD_B
#undef MM
}

extern "C" void kernel_launch(void* const* d_in, const int* in_sizes, int n_in,
                              void* d_out, int out_size, void* d_ws, size_t ws_size,
                              hipStream_t stream) {
    const int*   ids = (const int*)d_in[0];
    const float* mem = (const float*)d_in[1];
    const float* emb = (const float*)d_in[2];
    const float* Wq  = (const float*)d_in[3];
    const float* bq  = (const float*)d_in[4];
    const float* Ws  = (const float*)d_in[5];
    const float* bs  = (const float*)d_in[6];
    const float* Wk  = (const float*)d_in[7];
    const float* bk  = (const float*)d_in[8];
    float* out = (float*)d_out;

    unsigned short* x  = (unsigned short*)d_ws;              // 65536*1024 bf16 = 128 MiB
    unsigned short* wt = x + (size_t)BATCH_N * KDIM;         // 1536*1024  bf16 = 3 MiB

    hipLaunchKernelGGL(wconv_kernel, dim3(NTOT), dim3(256), 0, stream, Wq, Ws, Wk, wt);
    hipLaunchKernelGGL(prep_kernel, dim3(BATCH_N / 4), dim3(256), 0, stream, ids, mem, emb, x);
    hipLaunchKernelGGL(gemm_kernel, dim3(NWG), dim3(512), 0, stream,
                       x, wt, bq, bs, bk, out);
}